// Round 17
// baseline (248.841 us; speedup 1.0000x reference)
//
#include <hip/hip_runtime.h>
#include <math.h>

// ---------------------------------------------------------------------------
// PointCloudPerceiverChannelsEncoder — round 16: flatten gconv into
// throughput dispatches: im2col to global + dense conv GEMMs via bgemm16.
//   im2col1 -> conv1 GEMM (M=8192,K=1152) -> im2col2 -> conv2 GEMM
//   (M=9216,K=1024) -> redmean; kvln standalone. Everything else = R15.
// ---------------------------------------------------------------------------

namespace {

constexpr int NP = 8192;
constexpr int WD = 128;
constexpr int POSD = 62;
constexpr float R2C = 0.04f;
constexpr float QSCALE = 0.17677669529663687f;    // 1/sqrt(32)
constexpr float HALFPI = 1.5707963705062866f;

typedef __bf16 bf16x8 __attribute__((ext_vector_type(8)));
typedef float f32x4 __attribute__((ext_vector_type(4)));
union U16B { uint4 u; bf16x8 h; unsigned short s[8]; };

__device__ __forceinline__ float b2f(unsigned short u) {
  unsigned v = (unsigned)u << 16;
  return __builtin_bit_cast(float, v);
}

// bf16 weight arena element offsets (ushort units)
constexpr size_t AO_WQ     = 0;
constexpr size_t AO_WKV    = 16384;
constexpr size_t AO_WPROJC = 49152;
constexpr size_t AO_WMLP1C = 65536;
constexpr size_t AO_WMLP2C = 131072;
constexpr size_t AO_WQKVS  = 196608;
constexpr size_t AO_WPROJS = 344064;
constexpr size_t AO_WMLP1S = 393216;
constexpr size_t AO_WMLP2S = 589824;
constexpr size_t AO_WOUT   = 786432;
constexpr size_t AO_W1B    = 802816;   // [128][1152] (1040 real + zero pad)
constexpr size_t AO_W2B    = 950272;   // [128][1024]
constexpr size_t AO_TOT    = 1081344;

// ---------------- posenc + pe GEMM: emb[65536][128] bf16 --------------------
__global__ __launch_bounds__(256) void k_posenc(
    const float* __restrict__ pts, const float* __restrict__ pew,
    const float* __restrict__ peb, unsigned short* __restrict__ embb) {
  __shared__ float posT[62][36];
  const int tid = threadIdx.x;
  const int base = blockIdx.x * 32;
  for (int i = tid; i < 32 * POSD; i += 256) {
    int p = i / POSD, j = i % POSD;
    const float* pp = pts + (size_t)(base + p) * 2;
    float v;
    if (j < 2) {
      v = pp[j];
    } else if (j < 32) {
      int t = j - 2;
      v = sinf(pp[t & 1] * (float)(1 << (t >> 1)));
    } else {
      int t = j - 32;
      v = sinf(pp[t & 1] * (float)(1 << (t >> 1)) + HALFPI);
    }
    posT[j][p] = v;
  }
  __syncthreads();
  const int c = tid & 127, pg = tid >> 7;
  float acc[16];
  const float bias = peb[c];
#pragma unroll
  for (int k = 0; k < 16; ++k) acc[k] = bias;
  for (int j = 0; j < POSD; ++j) {
    float w = pew[j * WD + c];
    const float4 p0 = *(const float4*)&posT[j][pg * 16];
    const float4 p1 = *(const float4*)&posT[j][pg * 16 + 4];
    const float4 p2 = *(const float4*)&posT[j][pg * 16 + 8];
    const float4 p3 = *(const float4*)&posT[j][pg * 16 + 12];
    acc[0] += p0.x * w;  acc[1] += p0.y * w;
    acc[2] += p0.z * w;  acc[3] += p0.w * w;
    acc[4] += p1.x * w;  acc[5] += p1.y * w;
    acc[6] += p1.z * w;  acc[7] += p1.w * w;
    acc[8] += p2.x * w;  acc[9] += p2.y * w;
    acc[10] += p2.z * w; acc[11] += p2.w * w;
    acc[12] += p3.x * w; acc[13] += p3.y * w;
    acc[14] += p3.z * w; acc[15] += p3.w * w;
  }
#pragma unroll
  for (int k = 0; k < 16; ++k) {
    __bf16 bv = (__bf16)acc[k];
    embb[(size_t)(base + pg * 16 + k) * WD + c] = *(unsigned short*)&bv;
  }
}

// ---------------- mega-prep: all weights -> bf16 arena ----------------------
__global__ __launch_bounds__(256) void k_prep(
    const float* __restrict__ wq, const float* __restrict__ wkv,
    const float* __restrict__ wprojc, const float* __restrict__ wmlp1c,
    const float* __restrict__ wmlp2c, const float* __restrict__ wqkvs,
    const float* __restrict__ wprojs, const float* __restrict__ wmlp1s,
    const float* __restrict__ wmlp2s, const float* __restrict__ wout,
    const float* __restrict__ w1, const float* __restrict__ w2,
    unsigned short* __restrict__ dst) {
  const size_t i = (size_t)blockIdx.x * 256 + threadIdx.x;
  if (i >= AO_TOT) return;
  float v;
  if (i < AO_WKV) {
    size_t j = i;            v = wq[(j & 127) * 128 + (j >> 7)];
  } else if (i < AO_WPROJC) {
    size_t j = i - AO_WKV;   v = wkv[(j & 127) * 256 + (j >> 7)];
  } else if (i < AO_WMLP1C) {
    size_t j = i - AO_WPROJC; v = wprojc[(j & 127) * 128 + (j >> 7)];
  } else if (i < AO_WMLP2C) {
    size_t j = i - AO_WMLP1C; v = wmlp1c[(j & 127) * 512 + (j >> 7)];
  } else if (i < AO_WQKVS) {
    size_t j = i - AO_WMLP2C; v = wmlp2c[(j & 511) * 128 + (j >> 9)];
  } else if (i < AO_WPROJS) {
    size_t j = i - AO_WQKVS;
    size_t L = j / 49152, jj = j % 49152;
    v = wqkvs[L * 49152 + (jj & 127) * 384 + (jj >> 7)];
  } else if (i < AO_WMLP1S) {
    size_t j = i - AO_WPROJS;
    size_t L = j / 16384, jj = j % 16384;
    v = wprojs[L * 16384 + (jj & 127) * 128 + (jj >> 7)];
  } else if (i < AO_WMLP2S) {
    size_t j = i - AO_WMLP1S;
    size_t L = j / 65536, jj = j % 65536;
    v = wmlp1s[L * 65536 + (jj & 127) * 512 + (jj >> 7)];
  } else if (i < AO_WOUT) {
    size_t j = i - AO_WMLP2S;
    size_t L = j / 65536, jj = j % 65536;
    v = wmlp2s[L * 65536 + (jj & 511) * 128 + (jj >> 9)];
  } else if (i < AO_W1B) {
    size_t j = i - AO_WOUT;  v = wout[(j & 127) * 128 + (j >> 7)];
  } else if (i < AO_W2B) {                // conv1 [c][1152], zero-padded
    size_t j = i - AO_W1B;
    size_t c = j / 1152, k = j % 1152;
    v = (k < 1040) ? w1[c * 1040 + k] : 0.f;
  } else {                                // conv2 [c][1024]
    size_t j = i - AO_W2B;   v = w2[(j >> 10) * 1024 + (j & 1023)];
  }
  __bf16 bv = (__bf16)v;
  dst[i] = *(unsigned short*)&bv;
}

// ---------------- standalone single-pass KV LN-GEMM (grid 2048) -------------
__global__ __launch_bounds__(256) void k_kvln(
    const unsigned short* __restrict__ embb,
    const unsigned short* __restrict__ wkvt,
    const float* __restrict__ kvbias, unsigned short* __restrict__ kb,
    unsigned short* __restrict__ vb, const float* __restrict__ lnS,
    const float* __restrict__ lnB) {
  __shared__ unsigned short Ab[32][136];
  __shared__ unsigned short Bt[128][136];
  const int tid = threadIdx.x;
  const int w = tid >> 6, lane = tid & 63;
  const int l15 = lane & 15, l16 = lane >> 4;
  const size_t row0 = (size_t)blockIdx.x * 32;
  {
    const int n = tid >> 1, hf = tid & 1;
    const unsigned short* src = wkvt + ((size_t)n * 128 + hf * 64);
#pragma unroll
    for (int q8 = 0; q8 < 8; ++q8)
      *(uint4*)&Bt[n][hf * 64 + q8 * 8] = *(const uint4*)(src + q8 * 8);
  }
  {
    const int r = tid >> 3, seg = tid & 7;
    const unsigned short* ap = embb + (row0 + r) * WD + seg * 16;
    U16B w0, w1u;
    w0.u = *(const uint4*)ap;
    w1u.u = *(const uint4*)(ap + 8);
    float xv[16];
#pragma unroll
    for (int j = 0; j < 8; ++j) {
      xv[j] = b2f(w0.s[j]);
      xv[8 + j] = b2f(w1u.s[j]);
    }
    float s = 0.f, sq = 0.f;
#pragma unroll
    for (int j = 0; j < 16; ++j) { s += xv[j]; sq += xv[j] * xv[j]; }
    s += __shfl_xor(s, 1);  sq += __shfl_xor(sq, 1);
    s += __shfl_xor(s, 2);  sq += __shfl_xor(sq, 2);
    s += __shfl_xor(s, 4);  sq += __shfl_xor(sq, 4);
    const float m = s * (1.f / 128.f);
    const float var = fmaxf(sq * (1.f / 128.f) - m * m, 0.f);
    const float rinv = 1.0f / sqrtf(var + 1e-5f);
    U16B u0, u1;
#pragma unroll
    for (int j = 0; j < 16; ++j) {
      int col = seg * 16 + j;
      float y = (xv[j] - m) * rinv * lnS[col] + lnB[col];
      if (j < 8) u0.h[j] = (__bf16)y; else u1.h[j - 8] = (__bf16)y;
    }
    *(uint4*)&Ab[r][seg * 16] = u0.u;
    *(uint4*)&Ab[r][seg * 16 + 8] = u1.u;
  }
  const int rt = w >> 1, ch = w & 1;
  for (int nb = 0; nb < 2; ++nb) {
    if (nb) {
      __syncthreads();
      const int n = tid >> 1, hf = tid & 1;
      const unsigned short* src = wkvt + ((size_t)(128 + n) * 128 + hf * 64);
#pragma unroll
      for (int q8 = 0; q8 < 8; ++q8)
        *(uint4*)&Bt[n][hf * 64 + q8 * 8] = *(const uint4*)(src + q8 * 8);
    }
    __syncthreads();
    f32x4 acc[4];
#pragma unroll
    for (int j = 0; j < 4; ++j) acc[j] = (f32x4){0.f, 0.f, 0.f, 0.f};
#pragma unroll
    for (int kk = 0; kk < 4; ++kk) {
      U16B ua;
      ua.u = *(const uint4*)&Ab[rt * 16 + l15][kk * 32 + l16 * 8];
#pragma unroll
      for (int ct4 = 0; ct4 < 4; ++ct4) {
        U16B ub;
        ub.u = *(const uint4*)&Bt[(ch * 4 + ct4) * 16 + l15][kk * 32 + l16 * 8];
        acc[ct4] = __builtin_amdgcn_mfma_f32_16x16x32_bf16(ua.h, ub.h,
                                                           acc[ct4], 0, 0, 0);
      }
    }
    unsigned short* Dp = nb ? vb : kb;
#pragma unroll
    for (int ct4 = 0; ct4 < 4; ++ct4) {
      int colL = (ch * 4 + ct4) * 16 + l15;
      float bv = kvbias[nb * 128 + colL];
#pragma unroll
      for (int r = 0; r < 4; ++r) {
        size_t row = row0 + rt * 16 + l16 * 4 + r;
        __bf16 ov = (__bf16)(acc[ct4][r] + bv);
        Dp[row * 128 + colL] = *(unsigned short*)&ov;
      }
    }
  }
}

// ---------------- im2col1: ballquery + gather + B1 rows ---------------------
// grid = 1024 (one point), block = 256. B1g[(pt*8+h)][1152] bf16.
__global__ __launch_bounds__(256) void k_im2col1(
    const float* __restrict__ pts, const unsigned short* __restrict__ embb,
    unsigned short* __restrict__ B1g) {
  __shared__ unsigned short ft[132][8];
  __shared__ int sid[8];
  __shared__ int wcnt[4];
  const int bx = blockIdx.x;            // pt_g = b*128 + i
  const int b = bx >> 7, i = bx & 127;
  const int tid = threadIdx.x;
  const int w = tid >> 6, lane = tid & 63;
  // block-wide ballquery (256 candidates/iter)
  const float cx = pts[((size_t)b * NP + i) * 2];
  const float cy = pts[((size_t)b * NP + i) * 2 + 1];
  int cnt = 0;
  for (int j0 = 0; j0 < NP; j0 += 256) {
    const int j = j0 + tid;
    float dx = pts[((size_t)b * NP + j) * 2] - cx;
    float dy = pts[((size_t)b * NP + j) * 2 + 1] - cy;
    float d2 = __fadd_rn(__fmul_rn(dx, dx), __fmul_rn(dy, dy));
    bool ok = !(d2 > R2C);
    unsigned long long m = __ballot(ok);
    if (lane == 0) wcnt[w] = (int)__popcll(m);
    __syncthreads();
    int pre = cnt, tot = cnt;
#pragma unroll
    for (int ww = 0; ww < 4; ++ww) {
      int c4 = wcnt[ww];
      if (ww < w) pre += c4;
      tot += c4;
    }
    if (ok) {
      int ord = pre + (int)__popcll(m & ((1ull << lane) - 1ull));
      if (ord < 8) sid[ord] = j;
    }
    __syncthreads();
    cnt = tot;
    if (cnt >= 8) break;
  }
  if (tid >= cnt && tid < 8) sid[tid] = sid[0];
  __syncthreads();
  // gather: 8 rows x 128 ch (bf16) + xyz diffs + zero pad cins
  {
    const int s = tid >> 5, c4 = tid & 31;
    uint2 u = *(const uint2*)(embb + ((size_t)b * NP + sid[s]) * WD + c4 * 4);
    const unsigned short* us = (const unsigned short*)&u;
#pragma unroll
    for (int j2 = 0; j2 < 4; ++j2) ft[2 + c4 * 4 + j2][s] = us[j2];
  }
  if (tid < 16) {
    int s = tid >> 1, d = tid & 1;
    float dv = pts[((size_t)b * NP + sid[s]) * 2 + d] -
               pts[((size_t)b * NP + i) * 2 + d];
    __bf16 bv = (__bf16)dv;
    ft[d][s] = *(unsigned short*)&bv;
  } else if (tid < 32) {
    int idx = tid - 16;
    ft[130 + (idx >> 3)][idx & 7] = 0;
  }
  __syncthreads();
  // build 8 h-rows of 1152 (cin-major uint4: 8 p-values each)
  for (int h = 0; h < 8; ++h) {
    if (tid < 144) {
      U16B u;
      if (tid < 132) {
        U16B f;
        f.u = *(const uint4*)&ft[tid][0];
#pragma unroll
        for (int p = 0; p < 8; ++p) u.s[p] = f.s[(h + p + 4) & 7];
      } else {
        u.u.x = u.u.y = u.u.z = u.u.w = 0;
      }
      *(uint4*)&B1g[((size_t)bx * 8 + h) * 1152 + tid * 8] = u.u;
    }
  }
}

// ---------------- im2col2: B2 rows from y1 ----------------------------------
// grid = 9216 (row = pt*9 + h2), block = 128 (c1).
__global__ __launch_bounds__(128) void k_im2col2(
    const unsigned short* __restrict__ y1g, unsigned short* __restrict__ B2g) {
  const int bx = blockIdx.x;
  const int pt = bx / 9, h2 = bx % 9;
  const int c1 = threadIdx.x;
  U16B u;
#pragma unroll
  for (int p = 0; p < 8; ++p) {
    int hs = (h2 + p + 5) % 9;
    if (hs == 8) hs = 0;                // y[8] duplicates y[0]
    u.s[p] = y1g[((size_t)pt * 8 + hs) * 128 + c1];
  }
  *(uint4*)&B2g[(size_t)bx * 1024 + c1 * 8] = u.u;
}

// ---------------- redmean: weighted mean over 10 h (h2=0 twice) -------------
// grid = 512, block = 256. thread = (pt, c).
__global__ __launch_bounds__(256) void k_redmean(
    const float* __restrict__ y2g, float* __restrict__ dtok) {
  const int idx = blockIdx.x * 256 + threadIdx.x;   // 1024*128
  const int pt = idx >> 7, c = idx & 127;
  float s = y2g[((size_t)pt * 9) * 128 + c];        // h2=0 extra count
#pragma unroll
  for (int h2 = 0; h2 < 9; ++h2) s += y2g[((size_t)pt * 9 + h2) * 128 + c];
  dtok[(size_t)idx] = s / 10.0f;
}

// ---------------- concat(data_tokens, latents) + ln_pre -> h ---------------
__global__ __launch_bounds__(64) void k_concat_ln(
    const float* __restrict__ dtok, const float* __restrict__ otok,
    const float* __restrict__ g, const float* __restrict__ bta,
    float* __restrict__ h0) {
  const int row = blockIdx.x;
  const int b = row >> 8, t = row & 255;
  const int lane = threadIdx.x;
  const float* src = (t < 128) ? (dtok + ((size_t)b * 128 + t) * WD)
                               : (otok + (size_t)(t - 128) * WD);
  const float2 x2 = *(const float2*)(src + lane * 2);
  float s = x2.x + x2.y;
  float sq = x2.x * x2.x + x2.y * x2.y;
#pragma unroll
  for (int o = 1; o < 64; o <<= 1) {
    s += __shfl_xor(s, o);
    sq += __shfl_xor(sq, o);
  }
  float m = s * (1.f / 128.f);
  float var = fmaxf(sq * (1.f / 128.f) - m * m, 0.f);
  float r = 1.0f / sqrtf(var + 1e-5f);
  int c = lane * 2;
  float2 o2;
  o2.x = (x2.x - m) * r * g[c] + bta[c];
  o2.y = (x2.y - m) * r * g[c + 1] + bta[c + 1];
  *(float2*)(h0 + (size_t)row * WD + c) = o2;
}

// ---------------- bf16 MFMA GEMM, 16x64 tiles ------------------------------
// act: 0 none, 1 gelu, 2 tanh, 3 silu.
template <int ABF, int OBF, int COMB>
__global__ __launch_bounds__(256) void k_bgemm16(
    const void* __restrict__ A, int lda, const unsigned short* __restrict__ wt,
    const float* __restrict__ bias, const float* __restrict__ res, int ldres,
    void* __restrict__ D, int ldd, int K, int act,
    const float* __restrict__ lnS, const float* __restrict__ lnB, int keep,
    int skip, float oscale, int scaleCols,
    const unsigned short* __restrict__ opart, const float* __restrict__ lbuf,
    int S) {
  __shared__ unsigned short Ab[16][136];
  __shared__ unsigned short Bt[64][136];
  const int tid = threadIdx.x;
  const int row0 = blockIdx.x * 16;
  const int col0 = blockIdx.y * 64;
  const int w = tid >> 6, lane = tid & 63;
  const int l15 = lane & 15, l16 = lane >> 4;
  f32x4 acc = (f32x4){0.f, 0.f, 0.f, 0.f};
  for (int kt = 0; kt < K; kt += 128) {
    if (kt) __syncthreads();
    {
      const int n = tid >> 2, q = tid & 3;
      const unsigned short* src = wt + (size_t)(col0 + n) * K + kt + q * 32;
      *(uint4*)&Bt[n][q * 32] = *(const uint4*)src;
      *(uint4*)&Bt[n][q * 32 + 8] = *(const uint4*)(src + 8);
      *(uint4*)&Bt[n][q * 32 + 16] = *(const uint4*)(src + 16);
      *(uint4*)&Bt[n][q * 32 + 24] = *(const uint4*)(src + 24);
    }
    {
      const int r = tid >> 4, seg = tid & 15;
      const int grow = row0 + r;
      if (COMB) {
        const int bq = grow >> 8, q = grow & 255;
        const int h = seg >> 2, d0 = (seg & 3) * 8;
        const int pb = (bq * 4 + h) * S;
        float L = 0.f;
        float vals[8] = {0.f, 0.f, 0.f, 0.f, 0.f, 0.f, 0.f, 0.f};
        for (int s = 0; s < S; ++s) {
          L += lbuf[(size_t)(pb + s) * 256 + q];
          uint4 p4 = *(const uint4*)(opart + (size_t)(pb + s) * 8192 + q * 32 + d0);
          const unsigned short* ps = (const unsigned short*)&p4;
#pragma unroll
          for (int j = 0; j < 8; ++j) vals[j] += b2f(ps[j]);
        }
        const float inv = 1.0f / L;
        U16B u0;
#pragma unroll
        for (int j = 0; j < 8; ++j) u0.h[j] = (__bf16)(vals[j] * inv);
        *(uint4*)&Ab[r][seg * 8] = u0.u;
      } else if (ABF) {
        const int srow = (grow / keep) * (keep + skip) + skip + grow % keep;
        const unsigned short* ap =
            (const unsigned short*)A + (size_t)srow * lda + kt + seg * 8;
        *(uint4*)&Ab[r][seg * 8] = *(const uint4*)ap;
      } else {
        const int srow = (grow / keep) * (keep + skip) + skip + grow % keep;
        const float* ap = (const float*)A + (size_t)srow * lda + kt + seg * 8;
        float4 v0 = *(const float4*)ap;
        float4 v1 = *(const float4*)(ap + 4);
        float xv[8] = {v0.x, v0.y, v0.z, v0.w, v1.x, v1.y, v1.z, v1.w};
        if (lnS != nullptr) {
          float s = 0.f, sq = 0.f;
#pragma unroll
          for (int j = 0; j < 8; ++j) { s += xv[j]; sq += xv[j] * xv[j]; }
          s += __shfl_xor(s, 1);  sq += __shfl_xor(sq, 1);
          s += __shfl_xor(s, 2);  sq += __shfl_xor(sq, 2);
          s += __shfl_xor(s, 4);  sq += __shfl_xor(sq, 4);
          s += __shfl_xor(s, 8);  sq += __shfl_xor(sq, 8);
          const float m = s * (1.f / 128.f);
          const float var = fmaxf(sq * (1.f / 128.f) - m * m, 0.f);
          const float rinv = 1.0f / sqrtf(var + 1e-5f);
#pragma unroll
          for (int j = 0; j < 8; ++j) {
            int col = seg * 8 + j;
            xv[j] = (xv[j] - m) * rinv * lnS[col] + lnB[col];
          }
        }
        U16B u0;
#pragma unroll
        for (int j = 0; j < 8; ++j) u0.h[j] = (__bf16)xv[j];
        *(uint4*)&Ab[r][seg * 8] = u0.u;
      }
    }
    __syncthreads();
#pragma unroll
    for (int kk = 0; kk < 4; ++kk) {
      U16B ua, ub;
      ua.u = *(const uint4*)&Ab[l15][kk * 32 + l16 * 8];
      ub.u = *(const uint4*)&Bt[w * 16 + l15][kk * 32 + l16 * 8];
      acc = __builtin_amdgcn_mfma_f32_16x16x32_bf16(ua.h, ub.h, acc, 0, 0, 0);
    }
  }
  {
    const int colL = w * 16 + l15;
    const int col = col0 + colL;
    const float bv = bias[col];
#pragma unroll
    for (int r = 0; r < 4; ++r) {
      const int row = row0 + l16 * 4 + r;
      float x = acc[r] + bv;
      if (col0 < scaleCols) x *= oscale;
      if (act == 1) x = 0.5f * x * (1.0f + erff(x * 0.7071067811865476f));
      else if (act == 2) x = tanhf(x);
      else if (act == 3) x = x / (1.f + __expf(-x));
      if (res != nullptr) x += res[(size_t)row * ldres + col];
      if (OBF) {
        __bf16 ov = (__bf16)x;
        ((unsigned short*)D)[(size_t)row * ldd + col] = *(unsigned short*)&ov;
      } else {
        ((float*)D)[(size_t)row * ldd + col] = x;
      }
    }
  }
}

// ---------------- MFMA bf16 flash attention (maxless), split-K -------------
__global__ __launch_bounds__(256) void k_attn_mfma(
    const unsigned short* __restrict__ Q, int qs,
    const unsigned short* __restrict__ K, int ks,
    const unsigned short* __restrict__ V, int vs,
    unsigned short* __restrict__ opart, float* __restrict__ lbuf, int Tk,
    int S, int CH) {
  const int bx = blockIdx.x;
  const int s = bx % S;
  const int bh = bx / S;
  const int h = bh & 3, b = bh >> 2;
  const int tid = threadIdx.x;
  const int w = tid >> 6, lane = tid & 63;
  const int l15 = lane & 15, l16 = lane >> 4;

  __shared__ unsigned short Vt[32 * 68];
  __shared__ unsigned short Pl[4][16 * 72];

  bf16x8 qf[4];
#pragma unroll
  for (int m = 0; m < 4; ++m) {
    U16B u;
    u.u = *(const uint4*)(Q + (size_t)(b * 256 + w * 64 + m * 16 + l15) * qs +
                          h * 32 + l16 * 8);
    qf[m] = u.h;
  }
  U16B uones;
#pragma unroll
  for (int j = 0; j < 8; ++j) uones.h[j] = (__bf16)1.0f;
  const bf16x8 ones = uones.h;

  f32x4 o[4][2];
#pragma unroll
  for (int m = 0; m < 4; ++m)
#pragma unroll
    for (int d = 0; d < 2; ++d) o[m][d] = (f32x4){0.f, 0.f, 0.f, 0.f};
  f32x4 lsum[4];
#pragma unroll
  for (int m = 0; m < 4; ++m) lsum[m] = (f32x4){0.f, 0.f, 0.f, 0.f};

  const int kt0 = s * CH;
  for (int kt = kt0; kt < kt0 + CH; kt += 64) {
    __syncthreads();
    {
      const int r = tid >> 2, c0 = (tid & 3) * 8;
      const unsigned short* vp =
          V + (size_t)(b * Tk + kt + r) * vs + h * 32 + c0;
      U16B uv;
      uv.u = *(const uint4*)vp;
#pragma unroll
      for (int j = 0; j < 8; ++j) Vt[(c0 + j) * 68 + r] = uv.s[j];
    }
    __syncthreads();

    bf16x8 kf[4];
#pragma unroll
    for (int ksb = 0; ksb < 4; ++ksb) {
      U16B u;
      u.u = *(const uint4*)(K + (size_t)(b * Tk + kt + ksb * 16 + l15) * ks +
                            h * 32 + l16 * 8);
      kf[ksb] = u.h;
    }
    bf16x8 vf[2][2];
#pragma unroll
    for (int kc = 0; kc < 2; ++kc)
#pragma unroll
      for (int d = 0; d < 2; ++d) {
        const unsigned short* vp =
            &Vt[(l15 + 16 * d) * 68 + kc * 32 + l16 * 8];
        U16B u;
        *(uint2*)&u.s[0] = *(const uint2*)vp;
        *(uint2*)&u.s[4] = *(const uint2*)(vp + 4);
        vf[kc][d] = u.h;
      }

#pragma unroll
    for (int m = 0; m < 4; ++m) {
      const f32x4 zf = {0.f, 0.f, 0.f, 0.f};
      f32x4 sf[4];
#pragma unroll
      for (int ksb = 0; ksb < 4; ++ksb)
        sf[ksb] = __builtin_amdgcn_mfma_f32_16x16x32_bf16(qf[m], kf[ksb], zf,
                                                          0, 0, 0);
#pragma unroll
      for (int ksb = 0; ksb < 4; ++ksb)
#pragma unroll
        for (int r = 0; r < 4; ++r) {
          float p = __expf(sf[ksb][r]);
          __bf16 pb = (__bf16)p;
          Pl[w][(l16 * 4 + r) * 72 + ksb * 16 + l15] = *(unsigned short*)&pb;
        }
      asm volatile("s_waitcnt lgkmcnt(0)" ::: "memory");
      bf16x8 pa[2];
#pragma unroll
      for (int kc = 0; kc < 2; ++kc) {
        U16B u;
        u.u = *(const uint4*)&Pl[w][l15 * 72 + kc * 32 + l16 * 8];
        pa[kc] = u.h;
      }
      lsum[m] = __builtin_amdgcn_mfma_f32_16x16x32_bf16(pa[0], ones, lsum[m],
                                                        0, 0, 0);
      lsum[m] = __builtin_amdgcn_mfma_f32_16x16x32_bf16(pa[1], ones, lsum[m],
                                                        0, 0, 0);
#pragma unroll
      for (int kc = 0; kc < 2; ++kc)
#pragma unroll
        for (int d = 0; d < 2; ++d)
          o[m][d] = __builtin_amdgcn_mfma_f32_16x16x32_bf16(pa[kc], vf[kc][d],
                                                            o[m][d], 0, 0, 0);
    }
  }

  const size_t ob = (size_t)bx * 8192;
#pragma unroll
  for (int m = 0; m < 4; ++m) {
    int qrow = w * 64 + m * 16 + l16 * 4;
#pragma unroll
    for (int r = 0; r < 4; ++r) {
#pragma unroll
      for (int d = 0; d < 2; ++d) {
        __bf16 bo = (__bf16)o[m][d][r];
        opart[ob + (qrow + r) * 32 + d * 16 + l15] = *(unsigned short*)&bo;
      }
      if (l15 == 0) lbuf[(size_t)bx * 256 + qrow + r] = lsum[m][r];
    }
  }
}

}  // namespace

// ---------------------------------------------------------------------------
extern "C" void kernel_launch(void* const* d_in, const int* in_sizes, int n_in,
                              void* d_out, int out_size, void* d_ws,
                              size_t ws_size, hipStream_t stream) {
  const float* pts      = (const float*)d_in[0];
  const float* pe_w     = (const float*)d_in[1];
  const float* pe_b     = (const float*)d_in[2];
  const float* conv1_w  = (const float*)d_in[3];
  const float* conv1_b  = (const float*)d_in[4];
  const float* conv2_w  = (const float*)d_in[5];
  const float* conv2_b  = (const float*)d_in[6];
  const float* otok     = (const float*)d_in[7];
  const float* ln_pre_s = (const float*)d_in[8];
  const float* ln_pre_b = (const float*)d_in[9];
  const float* c_ln1_s  = (const float*)d_in[10];
  const float* c_ln1_b  = (const float*)d_in[11];
  const float* c_ln2_s  = (const float*)d_in[12];
  const float* c_ln2_b  = (const float*)d_in[13];
  const float* c_q_w    = (const float*)d_in[14];
  const float* c_q_b    = (const float*)d_in[15];
  const float* c_kv_w   = (const float*)d_in[16];
  const float* c_kv_b   = (const float*)d_in[17];
  const float* c_proj_w = (const float*)d_in[18];
  const float* c_proj_b = (const float*)d_in[19];
  const float* c_ln3_s  = (const float*)d_in[20];
  const float* c_ln3_b  = (const float*)d_in[21];
  const float* c_mlp1_w = (const float*)d_in[22];
  const float* c_mlp1_b = (const float*)d_in[23];
  const float* c_mlp2_w = (const float*)d_in[24];
  const float* c_mlp2_b = (const float*)d_in[25];
  const float* s_ln1_s  = (const float*)d_in[26];
  const float* s_ln1_b  = (const float*)d_in[27];
  const float* s_qkv_w  = (const float*)d_in[28];
  const float* s_qkv_b  = (const float*)d_in[29];
  const float* s_proj_w = (const float*)d_in[30];
  const float* s_proj_b = (const float*)d_in[31];
  const float* s_ln2_s  = (const float*)d_in[32];
  const float* s_ln2_b  = (const float*)d_in[33];
  const float* s_mlp1_w = (const float*)d_in[34];
  const float* s_mlp1_b = (const float*)d_in[35];
  const float* s_mlp2_w = (const float*)d_in[36];
  const float* s_mlp2_b = (const float*)d_in[37];
  const float* lnpost_s = (const float*)d_in[38];
  const float* lnpost_b = (const float*)d_in[39];
  const float* out_w    = (const float*)d_in[40];
  const float* out_b    = (const float*)d_in[41];

  char* ws = (char*)d_ws;
  constexpr size_t MB = 1024 * 1024;
  unsigned short* embb = (unsigned short*)(ws);             // 16 MB bf16
  unsigned short* kbuf = (unsigned short*)(ws + 32 * MB);   // 16 MB bf16
  unsigned short* vbuf = (unsigned short*)(ws + 48 * MB);   // 16 MB bf16
  char*  b3   = ws + 64 * MB;
  float* dtok = (float*)(b3);
  float* hbuf = (float*)(b3 + 524288);
  unsigned short* qbuf = (unsigned short*)(b3 + 524288 + 1048576);
  unsigned short* mid = (unsigned short*)(b3 + 524288 + 3145728);
  unsigned short* qkv = (unsigned short*)(b3 + 524288 + 7340032);
  unsigned short* arena = (unsigned short*)(b3 + 524288 + 10485760);
  unsigned short* opart = (unsigned short*)(ws);
  float* lbuf  = (float*)(b3 + 16 * MB);
  // conv pipeline scratch (dead before kvln writes kbuf/vbuf):
  unsigned short* B1g = (unsigned short*)(ws + 16 * MB);  // 18.9 MB (16-34.9)
  unsigned short* B2g = B1g;                              // reuse after gemm1
  unsigned short* y1g = (unsigned short*)(ws + 35 * MB);  // 2.1 MB
  float* y2g = (float*)(ws + 38 * MB);                    // 4.7 MB

  const int IDK = 1 << 28;

  // 1) weight prep (all bf16) + dataset_emb (bf16)
  k_prep<<<(int)((AO_TOT + 255) / 256), 256, 0, stream>>>(
      c_q_w, c_kv_w, c_proj_w, c_mlp1_w, c_mlp2_w, s_qkv_w, s_proj_w,
      s_mlp1_w, s_mlp2_w, out_w, conv1_w, conv2_w, arena);
  k_posenc<<<2048, 256, 0, stream>>>(pts, pe_w, pe_b, embb);
  // 2) conv pipeline: im2col1 -> conv1 GEMM -> im2col2 -> conv2 GEMM -> mean
  k_im2col1<<<1024, 256, 0, stream>>>(pts, embb, B1g);
  k_bgemm16<1, 1, 0><<<dim3(512, 2), 256, 0, stream>>>(
      B1g, 1152, arena + AO_W1B, conv1_b, nullptr, 0, y1g, 128, 1152, 3,
      nullptr, nullptr, IDK, 0, 1.f, 0, nullptr, nullptr, 0);
  k_im2col2<<<9216, 128, 0, stream>>>(y1g, B2g);
  k_bgemm16<1, 0, 0><<<dim3(576, 2), 256, 0, stream>>>(
      B2g, 1024, arena + AO_W2B, conv2_b, nullptr, 0, y2g, 128, 1024, 3,
      nullptr, nullptr, IDK, 0, 1.f, 0, nullptr, nullptr, 0);
  k_redmean<<<512, 256, 0, stream>>>(y2g, dtok);
  // 3) K,V (single-pass LN-GEMM, grid 2048) [last reader of embb]
  k_kvln<<<2048, 256, 0, stream>>>(embb, arena + AO_WKV, c_kv_b, kbuf, vbuf,
                                   c_ln2_s, c_ln2_b);
  // 4) concat + ln_pre -> h
  k_concat_ln<<<2048, 64, 0, stream>>>(dtok, otok, ln_pre_s, ln_pre_b, hbuf);
  // 5) cross attention block (S=32); Q pre-scaled bf16; comb fused into proj
  k_bgemm16<0, 1, 0><<<dim3(128, 2), 256, 0, stream>>>(
      hbuf, 128, arena + AO_WQ, c_q_b, nullptr, 0, qbuf, 128, 128, 0, c_ln1_s,
      c_ln1_b, IDK, 0, QSCALE, 128, nullptr, nullptr, 0);
  k_attn_mfma<<<1024, 256, 0, stream>>>(qbuf, 128, kbuf, 128, vbuf, 128,
                                        opart, lbuf, 8192, 32, 256);
  k_bgemm16<0, 0, 1><<<dim3(128, 2), 256, 0, stream>>>(
      nullptr, 128, arena + AO_WPROJC, c_proj_b, hbuf, 128, hbuf, 128, 128, 0,
      nullptr, nullptr, IDK, 0, 1.f, 0, opart, lbuf, 32);
  k_bgemm16<0, 1, 0><<<dim3(128, 8), 256, 0, stream>>>(
      hbuf, 128, arena + AO_WMLP1C, c_mlp1_b, nullptr, 0, mid, 512, 128, 1,
      c_ln3_s, c_ln3_b, IDK, 0, 1.f, 0, nullptr, nullptr, 0);
  k_bgemm16<1, 0, 0><<<dim3(128, 2), 256, 0, stream>>>(
      mid, 512, arena + AO_WMLP2C, c_mlp2_b, hbuf, 128, hbuf, 128, 512, 0,
      nullptr, nullptr, IDK, 0, 1.f, 0, nullptr, nullptr, 0);
  // 6) self-attention blocks (S=4), comb fused into proj
  for (int i = 0; i < 3; ++i) {
    k_bgemm16<0, 1, 0><<<dim3(128, 6), 256, 0, stream>>>(
        hbuf, 128, arena + AO_WQKVS + (size_t)i * 49152, s_qkv_b + i * 384,
        nullptr, 0, qkv, 384, 128, 0, s_ln1_s + i * 128, s_ln1_b + i * 128,
        IDK, 0, QSCALE, 128, nullptr, nullptr, 0);
    k_attn_mfma<<<128, 256, 0, stream>>>(qkv, 384, qkv + 128, 384, qkv + 256,
                                         384, opart, lbuf, 256, 4, 64);
    k_bgemm16<0, 0, 1><<<dim3(128, 2), 256, 0, stream>>>(
        nullptr, 128, arena + AO_WPROJS + (size_t)i * 16384,
        s_proj_b + i * 128, hbuf, 128, hbuf, 128, 128, 0, nullptr, nullptr,
        IDK, 0, 1.f, 0, opart, lbuf, 4);
    k_bgemm16<0, 1, 0><<<dim3(128, 8), 256, 0, stream>>>(
        hbuf, 128, arena + AO_WMLP1S + (size_t)i * 65536, s_mlp1_b + i * 512,
        nullptr, 0, mid, 512, 128, 1, s_ln2_s + i * 128, s_ln2_b + i * 128,
        IDK, 0, 1.f, 0, nullptr, nullptr, 0);
    k_bgemm16<1, 0, 0><<<dim3(128, 2), 256, 0, stream>>>(
        mid, 512, arena + AO_WMLP2S + (size_t)i * 65536, s_mlp2_b + i * 128,
        hbuf, 128, hbuf, 128, 512, 0, nullptr, nullptr, IDK, 0, 1.f, 0,
        nullptr, nullptr, 0);
  }
  // 7) final LN (last 128 tokens per batch) + output head with tanh
  k_bgemm16<0, 0, 0><<<dim3(64, 2), 256, 0, stream>>>(
      hbuf, 128, arena + AO_WOUT, out_b, nullptr, 0, (float*)d_out, 128, 128,
      2, lnpost_s, lnpost_b, 128, 128, 1.f, 0, nullptr, nullptr, 0);
}

// Round 18
// 231.306 us; speedup vs baseline: 1.0758x; 1.0758x over previous
//
#include <hip/hip_runtime.h>
#include <math.h>

// ---------------------------------------------------------------------------
// PointCloudPerceiverChannelsEncoder — round 17: RESTORE best config (= R15,
// 231.6us). R16 im2col-flattening regressed (248.8); all three structural
// exits from this configuration (R13 fusion, R14 coalesced stores, R16
// throughput-flattening) measured worse. This is the converged kernel.
// ---------------------------------------------------------------------------

namespace {

constexpr int NP = 8192;
constexpr int WD = 128;
constexpr int POSD = 62;
constexpr float R2C = 0.04f;
constexpr float QSCALE = 0.17677669529663687f;    // 1/sqrt(32)
constexpr float HALFPI = 1.5707963705062866f;

typedef __bf16 bf16x8 __attribute__((ext_vector_type(8)));
typedef float f32x4 __attribute__((ext_vector_type(4)));
union U16B { uint4 u; bf16x8 h; unsigned short s[8]; };

__device__ __forceinline__ float b2f(unsigned short u) {
  unsigned v = (unsigned)u << 16;
  return __builtin_bit_cast(float, v);
}

// bf16 weight arena element offsets (ushort units)
constexpr size_t AO_WQ     = 0;
constexpr size_t AO_WKV    = 16384;
constexpr size_t AO_WPROJC = 49152;
constexpr size_t AO_WMLP1C = 65536;
constexpr size_t AO_WMLP2C = 131072;
constexpr size_t AO_WQKVS  = 196608;
constexpr size_t AO_WPROJS = 344064;
constexpr size_t AO_WMLP1S = 393216;
constexpr size_t AO_WMLP2S = 589824;
constexpr size_t AO_WOUT   = 786432;
constexpr size_t AO_W1B    = 802816;   // [128][1056] (1040 + zero pad)
constexpr size_t AO_W2B    = 937984;   // [128][1024]
constexpr size_t AO_TOT    = 1069056;

// ---------------- posenc + pe GEMM: emb[65536][128] bf16 --------------------
__global__ __launch_bounds__(256) void k_posenc(
    const float* __restrict__ pts, const float* __restrict__ pew,
    const float* __restrict__ peb, unsigned short* __restrict__ embb) {
  __shared__ float posT[62][36];
  const int tid = threadIdx.x;
  const int base = blockIdx.x * 32;
  for (int i = tid; i < 32 * POSD; i += 256) {
    int p = i / POSD, j = i % POSD;
    const float* pp = pts + (size_t)(base + p) * 2;
    float v;
    if (j < 2) {
      v = pp[j];
    } else if (j < 32) {
      int t = j - 2;
      v = sinf(pp[t & 1] * (float)(1 << (t >> 1)));
    } else {
      int t = j - 32;
      v = sinf(pp[t & 1] * (float)(1 << (t >> 1)) + HALFPI);
    }
    posT[j][p] = v;
  }
  __syncthreads();
  const int c = tid & 127, pg = tid >> 7;
  float acc[16];
  const float bias = peb[c];
#pragma unroll
  for (int k = 0; k < 16; ++k) acc[k] = bias;
  for (int j = 0; j < POSD; ++j) {
    float w = pew[j * WD + c];
    const float4 p0 = *(const float4*)&posT[j][pg * 16];
    const float4 p1 = *(const float4*)&posT[j][pg * 16 + 4];
    const float4 p2 = *(const float4*)&posT[j][pg * 16 + 8];
    const float4 p3 = *(const float4*)&posT[j][pg * 16 + 12];
    acc[0] += p0.x * w;  acc[1] += p0.y * w;
    acc[2] += p0.z * w;  acc[3] += p0.w * w;
    acc[4] += p1.x * w;  acc[5] += p1.y * w;
    acc[6] += p1.z * w;  acc[7] += p1.w * w;
    acc[8] += p2.x * w;  acc[9] += p2.y * w;
    acc[10] += p2.z * w; acc[11] += p2.w * w;
    acc[12] += p3.x * w; acc[13] += p3.y * w;
    acc[14] += p3.z * w; acc[15] += p3.w * w;
  }
#pragma unroll
  for (int k = 0; k < 16; ++k) {
    __bf16 bv = (__bf16)acc[k];
    embb[(size_t)(base + pg * 16 + k) * WD + c] = *(unsigned short*)&bv;
  }
}

// ---------------- mega-prep: all weights -> bf16 arena ----------------------
__global__ __launch_bounds__(256) void k_prep(
    const float* __restrict__ wq, const float* __restrict__ wkv,
    const float* __restrict__ wprojc, const float* __restrict__ wmlp1c,
    const float* __restrict__ wmlp2c, const float* __restrict__ wqkvs,
    const float* __restrict__ wprojs, const float* __restrict__ wmlp1s,
    const float* __restrict__ wmlp2s, const float* __restrict__ wout,
    const float* __restrict__ w1, const float* __restrict__ w2,
    unsigned short* __restrict__ dst) {
  const size_t i = (size_t)blockIdx.x * 256 + threadIdx.x;
  if (i >= AO_TOT) return;
  float v;
  if (i < AO_WKV) {
    size_t j = i;            v = wq[(j & 127) * 128 + (j >> 7)];
  } else if (i < AO_WPROJC) {
    size_t j = i - AO_WKV;   v = wkv[(j & 127) * 256 + (j >> 7)];
  } else if (i < AO_WMLP1C) {
    size_t j = i - AO_WPROJC; v = wprojc[(j & 127) * 128 + (j >> 7)];
  } else if (i < AO_WMLP2C) {
    size_t j = i - AO_WMLP1C; v = wmlp1c[(j & 127) * 512 + (j >> 7)];
  } else if (i < AO_WQKVS) {
    size_t j = i - AO_WMLP2C; v = wmlp2c[(j & 511) * 128 + (j >> 9)];
  } else if (i < AO_WPROJS) {
    size_t j = i - AO_WQKVS;
    size_t L = j / 49152, jj = j % 49152;
    v = wqkvs[L * 49152 + (jj & 127) * 384 + (jj >> 7)];
  } else if (i < AO_WMLP1S) {
    size_t j = i - AO_WPROJS;
    size_t L = j / 16384, jj = j % 16384;
    v = wprojs[L * 16384 + (jj & 127) * 128 + (jj >> 7)];
  } else if (i < AO_WMLP2S) {
    size_t j = i - AO_WMLP1S;
    size_t L = j / 65536, jj = j % 65536;
    v = wmlp1s[L * 65536 + (jj & 127) * 512 + (jj >> 7)];
  } else if (i < AO_WOUT) {
    size_t j = i - AO_WMLP2S;
    size_t L = j / 65536, jj = j % 65536;
    v = wmlp2s[L * 65536 + (jj & 511) * 128 + (jj >> 9)];
  } else if (i < AO_W1B) {
    size_t j = i - AO_WOUT;  v = wout[(j & 127) * 128 + (j >> 7)];
  } else if (i < AO_W2B) {
    size_t j = i - AO_W1B;
    size_t c = j / 1056, k = j % 1056;
    v = (k < 1040) ? w1[c * 1040 + k] : 0.f;
  } else {
    size_t j = i - AO_W2B;   v = w2[(j >> 10) * 1024 + (j & 1023)];
  }
  __bf16 bv = (__bf16)v;
  dst[i] = *(unsigned short*)&bv;
}

// ---------------- merged dispatch: gconv (bx<256, 4pt) + kvln (bx>=256) -----
// kvln single-pass: LN rows once, compute K then V via W restage.
__global__ __launch_bounds__(256) void k_kvgc(
    const unsigned short* __restrict__ embb,
    const unsigned short* __restrict__ wkvt,
    const float* __restrict__ kvbias, unsigned short* __restrict__ kb,
    unsigned short* __restrict__ vb, const float* __restrict__ lnS,
    const float* __restrict__ lnB, const float* __restrict__ pts,
    const unsigned short* __restrict__ w1b, const float* __restrict__ b1,
    const unsigned short* __restrict__ w2b, const float* __restrict__ b2,
    float* __restrict__ dtok) {
  __shared__ __align__(16) char shl[43776];
  __shared__ int sid[4][8];
  const int bx = blockIdx.x;
  const int tid = threadIdx.x;
  const int w = tid >> 6, lane = tid & 63;
  const int l15 = lane & 15, l16 = lane >> 4;

  if (bx >= 256) {
    // ================= kvln branch (single-pass K+V) =================
    const int kx = bx - 256;                 // [0, 2048)
    const size_t row0 = (size_t)kx * 32;
    unsigned short (*Ab)[136] = (unsigned short(*)[136])shl;
    unsigned short (*Bt)[136] = (unsigned short(*)[136])(shl + 8704);
    // stage Bt for K (nb=0)
    {
      const int n = tid >> 1, hf = tid & 1;
      const unsigned short* src = wkvt + ((size_t)n * 128 + hf * 64);
#pragma unroll
      for (int q8 = 0; q8 < 8; ++q8)
        *(uint4*)&Bt[n][hf * 64 + q8 * 8] = *(const uint4*)(src + q8 * 8);
    }
    // stage Ab with LN (once)
    {
      const int r = tid >> 3, seg = tid & 7;
      const unsigned short* ap = embb + (row0 + r) * WD + seg * 16;
      U16B w0, w1u;
      w0.u = *(const uint4*)ap;
      w1u.u = *(const uint4*)(ap + 8);
      float xv[16];
#pragma unroll
      for (int j = 0; j < 8; ++j) {
        xv[j] = b2f(w0.s[j]);
        xv[8 + j] = b2f(w1u.s[j]);
      }
      float s = 0.f, sq = 0.f;
#pragma unroll
      for (int j = 0; j < 16; ++j) { s += xv[j]; sq += xv[j] * xv[j]; }
      s += __shfl_xor(s, 1);  sq += __shfl_xor(sq, 1);
      s += __shfl_xor(s, 2);  sq += __shfl_xor(sq, 2);
      s += __shfl_xor(s, 4);  sq += __shfl_xor(sq, 4);
      const float m = s * (1.f / 128.f);
      const float var = fmaxf(sq * (1.f / 128.f) - m * m, 0.f);
      const float rinv = 1.0f / sqrtf(var + 1e-5f);
      U16B u0, u1;
#pragma unroll
      for (int j = 0; j < 16; ++j) {
        int col = seg * 16 + j;
        float y = (xv[j] - m) * rinv * lnS[col] + lnB[col];
        if (j < 8) u0.h[j] = (__bf16)y; else u1.h[j - 8] = (__bf16)y;
      }
      *(uint4*)&Ab[r][seg * 16] = u0.u;
      *(uint4*)&Ab[r][seg * 16 + 8] = u1.u;
    }
    const int rt = w >> 1, ch = w & 1;
    for (int nb = 0; nb < 2; ++nb) {
      if (nb) {
        __syncthreads();   // previous MFMA Bt reads complete
        const int n = tid >> 1, hf = tid & 1;
        const unsigned short* src =
            wkvt + ((size_t)(128 + n) * 128 + hf * 64);
#pragma unroll
        for (int q8 = 0; q8 < 8; ++q8)
          *(uint4*)&Bt[n][hf * 64 + q8 * 8] = *(const uint4*)(src + q8 * 8);
      }
      __syncthreads();
      f32x4 acc[4];
#pragma unroll
      for (int j = 0; j < 4; ++j) acc[j] = (f32x4){0.f, 0.f, 0.f, 0.f};
#pragma unroll
      for (int kk = 0; kk < 4; ++kk) {
        U16B ua;
        ua.u = *(const uint4*)&Ab[rt * 16 + l15][kk * 32 + l16 * 8];
#pragma unroll
        for (int ct4 = 0; ct4 < 4; ++ct4) {
          U16B ub;
          ub.u =
              *(const uint4*)&Bt[(ch * 4 + ct4) * 16 + l15][kk * 32 + l16 * 8];
          acc[ct4] = __builtin_amdgcn_mfma_f32_16x16x32_bf16(ua.h, ub.h,
                                                             acc[ct4], 0, 0, 0);
        }
      }
      unsigned short* Dp = nb ? vb : kb;
#pragma unroll
      for (int ct4 = 0; ct4 < 4; ++ct4) {
        int colL = (ch * 4 + ct4) * 16 + l15;
        float bv = kvbias[nb * 128 + colL];
#pragma unroll
        for (int r = 0; r < 4; ++r) {
          size_t row = row0 + rt * 16 + l16 * 4 + r;
          __bf16 ov = (__bf16)(acc[ct4][r] + bv);
          Dp[row * 128 + colL] = *(unsigned short*)&ov;
        }
      }
    }
    return;
  }

  // ================= gconv branch (4 points/block) =================
  const int b = bx >> 5;
  const int i0 = (bx & 31) * 4;
  unsigned short* ftp  = (unsigned short*)shl;            // [4][132][8]
  unsigned short* Bt1p = (unsigned short*)(shl + 8448);   // 32 x 552
  unsigned short* y1p  = (unsigned short*)shl;            // [4][128][16]
  unsigned short* Bt2p = (unsigned short*)(shl + 16384);  // 38 x 264
  float* tmpp = (float*)(shl + 16384);                    // 36 x 132 f32

  {
    const int i = i0 + w;
    const float cx = pts[((size_t)b * NP + i) * 2];
    const float cy = pts[((size_t)b * NP + i) * 2 + 1];
    int cnt = 0;
    for (int j0 = 0; j0 < NP; j0 += 64) {
      int j = j0 + lane;
      float dx = pts[((size_t)b * NP + j) * 2] - cx;
      float dy = pts[((size_t)b * NP + j) * 2 + 1] - cy;
      float d2 = __fadd_rn(__fmul_rn(dx, dx), __fmul_rn(dy, dy));
      bool ok = !(d2 > R2C);
      unsigned long long m = __ballot(ok);
      int ord = cnt + __popcll(m & ((1ull << lane) - 1ull));
      if (ok && ord < 8) sid[w][ord] = j;
      cnt += (int)__popcll(m);
      if (cnt >= 8) break;
    }
    if (lane < 8 && lane >= cnt) sid[w][lane] = sid[w][0];
  }
  __syncthreads();
  {
    const int pr = tid >> 3, c16 = tid & 7;
    const int pt = pr >> 3, s = pr & 7;
    const unsigned short* src =
        embb + ((size_t)b * NP + sid[pt][s]) * WD + c16 * 16;
    U16B u0, u1;
    u0.u = *(const uint4*)src;
    u1.u = *(const uint4*)(src + 8);
#pragma unroll
    for (int j = 0; j < 8; ++j) {
      ftp[((size_t)pt * 132 + 2 + c16 * 16 + j) * 8 + s] = u0.s[j];
      ftp[((size_t)pt * 132 + 2 + c16 * 16 + 8 + j) * 8 + s] = u1.s[j];
    }
  }
  if (tid < 64) {
    int pt = tid >> 4, rem = tid & 15;
    int s = rem >> 1, d = rem & 1;
    float dv = pts[((size_t)b * NP + sid[pt][s]) * 2 + d] -
               pts[((size_t)b * NP + i0 + pt) * 2 + d];
    __bf16 bv = (__bf16)dv;
    ftp[((size_t)pt * 132 + d) * 8 + s] = *(unsigned short*)&bv;
    int pt2 = tid >> 4, cin2 = 130 + ((tid >> 3) & 1), s2 = tid & 7;
    ftp[((size_t)pt2 * 132 + cin2) * 8 + s2] = 0;
  }
  __syncthreads();
  f32x4 acc1[2][2];
#pragma unroll
  for (int t = 0; t < 2; ++t)
#pragma unroll
    for (int bt = 0; bt < 2; ++bt) acc1[t][bt] = (f32x4){0.f, 0.f, 0.f, 0.f};
  for (int ps = 0; ps < 2; ++ps) {
    const int cinbase = ps ? 68 : 0;
    const int CW = ps ? 64 : 68;
    if (ps) __syncthreads();
    {
      const int n = tid >> 3, g = tid & 7;
      const int pt = n >> 3, h = n & 7;
#pragma unroll
      for (int it = 0; it < 9; ++it) {
        int cl = g + it * 8;
        if (cl < CW) {
          int cin = cinbase + cl;
          U16B u0, u;
          u0.u = *(const uint4*)&ftp[((size_t)pt * 132 + cin) * 8];
#pragma unroll
          for (int p = 0; p < 8; ++p) u.s[p] = u0.s[(h + p + 4) & 7];
          *(uint4*)&Bt1p[n * 552 + cl * 8] = u.u;
        }
      }
    }
    __syncthreads();
    const unsigned short* w1r =
        w1b + (size_t)(w * 32 + l15) * 1056 + cinbase * 8;
    const int kit = ps ? 16 : 17;
    for (int ks = 0; ks < kit; ++ks) {
      const int k0 = ks * 32 + l16 * 8;
      U16B a0, a1, b0, b1u;
      a0.u = *(const uint4*)(w1r + k0);
      a1.u = *(const uint4*)(w1r + 16 * 1056 + k0);
      b0.u = *(const uint4*)&Bt1p[l15 * 552 + k0];
      b1u.u = *(const uint4*)&Bt1p[(16 + l15) * 552 + k0];
      acc1[0][0] = __builtin_amdgcn_mfma_f32_16x16x32_bf16(a0.h, b0.h,
                                                           acc1[0][0], 0, 0, 0);
      acc1[0][1] = __builtin_amdgcn_mfma_f32_16x16x32_bf16(a0.h, b1u.h,
                                                           acc1[0][1], 0, 0, 0);
      acc1[1][0] = __builtin_amdgcn_mfma_f32_16x16x32_bf16(a1.h, b0.h,
                                                           acc1[1][0], 0, 0, 0);
      acc1[1][1] = __builtin_amdgcn_mfma_f32_16x16x32_bf16(a1.h, b1u.h,
                                                           acc1[1][1], 0, 0, 0);
    }
  }
  __syncthreads();
  {
#pragma unroll
    for (int t = 0; t < 2; ++t)
#pragma unroll
      for (int bt = 0; bt < 2; ++bt) {
        const int n = bt * 16 + l15;
        const int pt = n >> 3, h = n & 7;
#pragma unroll
        for (int r = 0; r < 4; ++r) {
          int c = w * 32 + t * 16 + l16 * 4 + r;
          float x = acc1[t][bt][r] + b1[c];
          float sy = x / (1.f + __expf(-x));
          __bf16 bh = (__bf16)sy;
          unsigned short bits = *(unsigned short*)&bh;
          size_t yb = ((size_t)pt * 128 + c) * 16;
          y1p[yb + h] = bits;
          if (h == 0) y1p[yb + 8] = bits;
        }
      }
  }
  f32x4 acc2[2][3];
#pragma unroll
  for (int t = 0; t < 2; ++t)
#pragma unroll
    for (int bt = 0; bt < 3; ++bt) acc2[t][bt] = (f32x4){0.f, 0.f, 0.f, 0.f};
  for (int ps = 0; ps < 4; ++ps) {
    __syncthreads();
    {
      const int g = tid & 7;
      for (int n2 = tid >> 3; n2 < 38; n2 += 32) {
        const int pt = n2 / 9, h2 = n2 % 9;
#pragma unroll
        for (int it = 0; it < 4; ++it) {
          int cl = g + it * 8;
          U16B o;
          if (n2 < 36) {
            int c1 = ps * 32 + cl;
            size_t yb = ((size_t)pt * 128 + c1) * 16;
            U16B u0;
            u0.u = *(const uint4*)&y1p[yb];
            unsigned short yv[9];
#pragma unroll
            for (int j = 0; j < 8; ++j) yv[j] = u0.s[j];
            yv[8] = y1p[yb + 8];
#pragma unroll
            for (int p = 0; p < 8; ++p) o.s[p] = yv[(h2 + p + 5) % 9];
          } else {
            o.u.x = o.u.y = o.u.z = o.u.w = 0;
          }
          *(uint4*)&Bt2p[n2 * 264 + cl * 8] = o.u;
        }
      }
    }
    __syncthreads();
    const unsigned short* w2r =
        w2b + (size_t)(w * 32 + l15) * 1024 + ps * 256;
    int r2 = 32 + l15;
    if (r2 > 37) r2 = 37;
#pragma unroll
    for (int ks = 0; ks < 8; ++ks) {
      const int k0 = ks * 32 + l16 * 8;
      U16B a0, a1, b0, b1u, b2u;
      a0.u = *(const uint4*)(w2r + k0);
      a1.u = *(const uint4*)(w2r + 16 * 1024 + k0);
      b0.u = *(const uint4*)&Bt2p[l15 * 264 + k0];
      b1u.u = *(const uint4*)&Bt2p[(16 + l15) * 264 + k0];
      b2u.u = *(const uint4*)&Bt2p[r2 * 264 + k0];
      acc2[0][0] = __builtin_amdgcn_mfma_f32_16x16x32_bf16(a0.h, b0.h,
                                                           acc2[0][0], 0, 0, 0);
      acc2[0][1] = __builtin_amdgcn_mfma_f32_16x16x32_bf16(a0.h, b1u.h,
                                                           acc2[0][1], 0, 0, 0);
      acc2[0][2] = __builtin_amdgcn_mfma_f32_16x16x32_bf16(a0.h, b2u.h,
                                                           acc2[0][2], 0, 0, 0);
      acc2[1][0] = __builtin_amdgcn_mfma_f32_16x16x32_bf16(a1.h, b0.h,
                                                           acc2[1][0], 0, 0, 0);
      acc2[1][1] = __builtin_amdgcn_mfma_f32_16x16x32_bf16(a1.h, b1u.h,
                                                           acc2[1][1], 0, 0, 0);
      acc2[1][2] = __builtin_amdgcn_mfma_f32_16x16x32_bf16(a1.h, b2u.h,
                                                           acc2[1][2], 0, 0, 0);
    }
  }
  __syncthreads();
  {
#pragma unroll
    for (int t = 0; t < 2; ++t)
#pragma unroll
      for (int bt = 0; bt < 3; ++bt) {
        const int n2 = bt * 16 + l15;
        if (n2 < 36) {
          const int h2 = n2 % 9;
          const float wgt = (h2 == 0) ? 2.f : 1.f;
#pragma unroll
          for (int r = 0; r < 4; ++r) {
            int c = w * 32 + t * 16 + l16 * 4 + r;
            float x = acc2[t][bt][r] + b2[c];
            tmpp[n2 * 132 + c] = wgt * (x / (1.f + __expf(-x)));
          }
        }
      }
  }
  __syncthreads();
#pragma unroll
  for (int k = 0; k < 2; ++k) {
    int idx = tid + k * 256;
    int pt = idx >> 7, c = idx & 127;
    float ssum = 0.f;
#pragma unroll
    for (int h2 = 0; h2 < 9; ++h2) ssum += tmpp[(pt * 9 + h2) * 132 + c];
    dtok[((size_t)b * 128 + i0 + pt) * WD + c] = ssum / 10.0f;
  }
}

// ---------------- concat(data_tokens, latents) + ln_pre -> h ---------------
__global__ __launch_bounds__(64) void k_concat_ln(
    const float* __restrict__ dtok, const float* __restrict__ otok,
    const float* __restrict__ g, const float* __restrict__ bta,
    float* __restrict__ h0) {
  const int row = blockIdx.x;
  const int b = row >> 8, t = row & 255;
  const int lane = threadIdx.x;
  const float* src = (t < 128) ? (dtok + ((size_t)b * 128 + t) * WD)
                               : (otok + (size_t)(t - 128) * WD);
  const float2 x2 = *(const float2*)(src + lane * 2);
  float s = x2.x + x2.y;
  float sq = x2.x * x2.x + x2.y * x2.y;
#pragma unroll
  for (int o = 1; o < 64; o <<= 1) {
    s += __shfl_xor(s, o);
    sq += __shfl_xor(sq, o);
  }
  float m = s * (1.f / 128.f);
  float var = fmaxf(sq * (1.f / 128.f) - m * m, 0.f);
  float r = 1.0f / sqrtf(var + 1e-5f);
  int c = lane * 2;
  float2 o2;
  o2.x = (x2.x - m) * r * g[c] + bta[c];
  o2.y = (x2.y - m) * r * g[c + 1] + bta[c + 1];
  *(float2*)(h0 + (size_t)row * WD + c) = o2;
}

// ---------------- bf16 MFMA GEMM, 16x64 tiles ------------------------------
template <int ABF, int OBF, int COMB>
__global__ __launch_bounds__(256) void k_bgemm16(
    const void* __restrict__ A, int lda, const unsigned short* __restrict__ wt,
    const float* __restrict__ bias, const float* __restrict__ res, int ldres,
    void* __restrict__ D, int ldd, int K, int act,
    const float* __restrict__ lnS, const float* __restrict__ lnB, int keep,
    int skip, float oscale, int scaleCols,
    const unsigned short* __restrict__ opart, const float* __restrict__ lbuf,
    int S) {
  __shared__ unsigned short Ab[16][136];
  __shared__ unsigned short Bt[64][136];
  const int tid = threadIdx.x;
  const int row0 = blockIdx.x * 16;
  const int col0 = blockIdx.y * 64;
  const int w = tid >> 6, lane = tid & 63;
  const int l15 = lane & 15, l16 = lane >> 4;
  f32x4 acc = (f32x4){0.f, 0.f, 0.f, 0.f};
  for (int kt = 0; kt < K; kt += 128) {
    if (kt) __syncthreads();
    {
      const int n = tid >> 2, q = tid & 3;
      const unsigned short* src = wt + (size_t)(col0 + n) * K + kt + q * 32;
      *(uint4*)&Bt[n][q * 32] = *(const uint4*)src;
      *(uint4*)&Bt[n][q * 32 + 8] = *(const uint4*)(src + 8);
      *(uint4*)&Bt[n][q * 32 + 16] = *(const uint4*)(src + 16);
      *(uint4*)&Bt[n][q * 32 + 24] = *(const uint4*)(src + 24);
    }
    {
      const int r = tid >> 4, seg = tid & 15;
      const int grow = row0 + r;
      if (COMB) {
        const int bq = grow >> 8, q = grow & 255;
        const int h = seg >> 2, d0 = (seg & 3) * 8;
        const int pb = (bq * 4 + h) * S;
        float L = 0.f;
        float vals[8] = {0.f, 0.f, 0.f, 0.f, 0.f, 0.f, 0.f, 0.f};
        for (int s = 0; s < S; ++s) {
          L += lbuf[(size_t)(pb + s) * 256 + q];
          uint4 p4 = *(const uint4*)(opart + (size_t)(pb + s) * 8192 + q * 32 + d0);
          const unsigned short* ps = (const unsigned short*)&p4;
#pragma unroll
          for (int j = 0; j < 8; ++j) vals[j] += b2f(ps[j]);
        }
        const float inv = 1.0f / L;
        U16B u0;
#pragma unroll
        for (int j = 0; j < 8; ++j) u0.h[j] = (__bf16)(vals[j] * inv);
        *(uint4*)&Ab[r][seg * 8] = u0.u;
      } else if (ABF) {
        const int srow = (grow / keep) * (keep + skip) + skip + grow % keep;
        const unsigned short* ap =
            (const unsigned short*)A + (size_t)srow * lda + kt + seg * 8;
        *(uint4*)&Ab[r][seg * 8] = *(const uint4*)ap;
      } else {
        const int srow = (grow / keep) * (keep + skip) + skip + grow % keep;
        const float* ap = (const float*)A + (size_t)srow * lda + kt + seg * 8;
        float4 v0 = *(const float4*)ap;
        float4 v1 = *(const float4*)(ap + 4);
        float xv[8] = {v0.x, v0.y, v0.z, v0.w, v1.x, v1.y, v1.z, v1.w};
        if (lnS != nullptr) {
          float s = 0.f, sq = 0.f;
#pragma unroll
          for (int j = 0; j < 8; ++j) { s += xv[j]; sq += xv[j] * xv[j]; }
          s += __shfl_xor(s, 1);  sq += __shfl_xor(sq, 1);
          s += __shfl_xor(s, 2);  sq += __shfl_xor(sq, 2);
          s += __shfl_xor(s, 4);  sq += __shfl_xor(sq, 4);
          s += __shfl_xor(s, 8);  sq += __shfl_xor(sq, 8);
          const float m = s * (1.f / 128.f);
          const float var = fmaxf(sq * (1.f / 128.f) - m * m, 0.f);
          const float rinv = 1.0f / sqrtf(var + 1e-5f);
#pragma unroll
          for (int j = 0; j < 8; ++j) {
            int col = seg * 8 + j;
            xv[j] = (xv[j] - m) * rinv * lnS[col] + lnB[col];
          }
        }
        U16B u0;
#pragma unroll
        for (int j = 0; j < 8; ++j) u0.h[j] = (__bf16)xv[j];
        *(uint4*)&Ab[r][seg * 8] = u0.u;
      }
    }
    __syncthreads();
#pragma unroll
    for (int kk = 0; kk < 4; ++kk) {
      U16B ua, ub;
      ua.u = *(const uint4*)&Ab[l15][kk * 32 + l16 * 8];
      ub.u = *(const uint4*)&Bt[w * 16 + l15][kk * 32 + l16 * 8];
      acc = __builtin_amdgcn_mfma_f32_16x16x32_bf16(ua.h, ub.h, acc, 0, 0, 0);
    }
  }
  {
    const int colL = w * 16 + l15;
    const int col = col0 + colL;
    const float bv = bias[col];
#pragma unroll
    for (int r = 0; r < 4; ++r) {
      const int row = row0 + l16 * 4 + r;
      float x = acc[r] + bv;
      if (col0 < scaleCols) x *= oscale;
      if (act == 1) x = 0.5f * x * (1.0f + erff(x * 0.7071067811865476f));
      else if (act == 2) x = tanhf(x);
      if (res != nullptr) x += res[(size_t)row * ldres + col];
      if (OBF) {
        __bf16 ov = (__bf16)x;
        ((unsigned short*)D)[(size_t)row * ldd + col] = *(unsigned short*)&ov;
      } else {
        ((float*)D)[(size_t)row * ldd + col] = x;
      }
    }
  }
}

// ---------------- MFMA bf16 flash attention (maxless), split-K -------------
__global__ __launch_bounds__(256) void k_attn_mfma(
    const unsigned short* __restrict__ Q, int qs,
    const unsigned short* __restrict__ K, int ks,
    const unsigned short* __restrict__ V, int vs,
    unsigned short* __restrict__ opart, float* __restrict__ lbuf, int Tk,
    int S, int CH) {
  const int bx = blockIdx.x;
  const int s = bx % S;
  const int bh = bx / S;
  const int h = bh & 3, b = bh >> 2;
  const int tid = threadIdx.x;
  const int w = tid >> 6, lane = tid & 63;
  const int l15 = lane & 15, l16 = lane >> 4;

  __shared__ unsigned short Vt[32 * 68];
  __shared__ unsigned short Pl[4][16 * 72];

  bf16x8 qf[4];
#pragma unroll
  for (int m = 0; m < 4; ++m) {
    U16B u;
    u.u = *(const uint4*)(Q + (size_t)(b * 256 + w * 64 + m * 16 + l15) * qs +
                          h * 32 + l16 * 8);
    qf[m] = u.h;
  }
  U16B uones;
#pragma unroll
  for (int j = 0; j < 8; ++j) uones.h[j] = (__bf16)1.0f;
  const bf16x8 ones = uones.h;

  f32x4 o[4][2];
#pragma unroll
  for (int m = 0; m < 4; ++m)
#pragma unroll
    for (int d = 0; d < 2; ++d) o[m][d] = (f32x4){0.f, 0.f, 0.f, 0.f};
  f32x4 lsum[4];
#pragma unroll
  for (int m = 0; m < 4; ++m) lsum[m] = (f32x4){0.f, 0.f, 0.f, 0.f};

  const int kt0 = s * CH;
  for (int kt = kt0; kt < kt0 + CH; kt += 64) {
    __syncthreads();
    {
      const int r = tid >> 2, c0 = (tid & 3) * 8;
      const unsigned short* vp =
          V + (size_t)(b * Tk + kt + r) * vs + h * 32 + c0;
      U16B uv;
      uv.u = *(const uint4*)vp;
#pragma unroll
      for (int j = 0; j < 8; ++j) Vt[(c0 + j) * 68 + r] = uv.s[j];
    }
    __syncthreads();

    bf16x8 kf[4];
#pragma unroll
    for (int ksb = 0; ksb < 4; ++ksb) {
      U16B u;
      u.u = *(const uint4*)(K + (size_t)(b * Tk + kt + ksb * 16 + l15) * ks +
                            h * 32 + l16 * 8);
      kf[ksb] = u.h;
    }
    bf16x8 vf[2][2];
#pragma unroll
    for (int kc = 0; kc < 2; ++kc)
#pragma unroll
      for (int d = 0; d < 2; ++d) {
        const unsigned short* vp =
            &Vt[(l15 + 16 * d) * 68 + kc * 32 + l16 * 8];
        U16B u;
        *(uint2*)&u.s[0] = *(const uint2*)vp;
        *(uint2*)&u.s[4] = *(const uint2*)(vp + 4);
        vf[kc][d] = u.h;
      }

#pragma unroll
    for (int m = 0; m < 4; ++m) {
      const f32x4 zf = {0.f, 0.f, 0.f, 0.f};
      f32x4 sf[4];
#pragma unroll
      for (int ksb = 0; ksb < 4; ++ksb)
        sf[ksb] = __builtin_amdgcn_mfma_f32_16x16x32_bf16(qf[m], kf[ksb], zf,
                                                          0, 0, 0);
#pragma unroll
      for (int ksb = 0; ksb < 4; ++ksb)
#pragma unroll
        for (int r = 0; r < 4; ++r) {
          float p = __expf(sf[ksb][r]);
          __bf16 pb = (__bf16)p;
          Pl[w][(l16 * 4 + r) * 72 + ksb * 16 + l15] = *(unsigned short*)&pb;
        }
      asm volatile("s_waitcnt lgkmcnt(0)" ::: "memory");
      bf16x8 pa[2];
#pragma unroll
      for (int kc = 0; kc < 2; ++kc) {
        U16B u;
        u.u = *(const uint4*)&Pl[w][l15 * 72 + kc * 32 + l16 * 8];
        pa[kc] = u.h;
      }
      lsum[m] = __builtin_amdgcn_mfma_f32_16x16x32_bf16(pa[0], ones, lsum[m],
                                                        0, 0, 0);
      lsum[m] = __builtin_amdgcn_mfma_f32_16x16x32_bf16(pa[1], ones, lsum[m],
                                                        0, 0, 0);
#pragma unroll
      for (int kc = 0; kc < 2; ++kc)
#pragma unroll
        for (int d = 0; d < 2; ++d)
          o[m][d] = __builtin_amdgcn_mfma_f32_16x16x32_bf16(pa[kc], vf[kc][d],
                                                            o[m][d], 0, 0, 0);
    }
  }

  const size_t ob = (size_t)bx * 8192;
#pragma unroll
  for (int m = 0; m < 4; ++m) {
    int qrow = w * 64 + m * 16 + l16 * 4;
#pragma unroll
    for (int r = 0; r < 4; ++r) {
#pragma unroll
      for (int d = 0; d < 2; ++d) {
        __bf16 bo = (__bf16)o[m][d][r];
        opart[ob + (qrow + r) * 32 + d * 16 + l15] = *(unsigned short*)&bo;
      }
      if (l15 == 0) lbuf[(size_t)bx * 256 + qrow + r] = lsum[m][r];
    }
  }
}

}  // namespace

// ---------------------------------------------------------------------------
extern "C" void kernel_launch(void* const* d_in, const int* in_sizes, int n_in,
                              void* d_out, int out_size, void* d_ws,
                              size_t ws_size, hipStream_t stream) {
  const float* pts      = (const float*)d_in[0];
  const float* pe_w     = (const float*)d_in[1];
  const float* pe_b     = (const float*)d_in[2];
  const float* conv1_w  = (const float*)d_in[3];
  const float* conv1_b  = (const float*)d_in[4];
  const float* conv2_w  = (const float*)d_in[5];
  const float* conv2_b  = (const float*)d_in[6];
  const float* otok     = (const float*)d_in[7];
  const float* ln_pre_s = (const float*)d_in[8];
  const float* ln_pre_b = (const float*)d_in[9];
  const float* c_ln1_s  = (const float*)d_in[10];
  const float* c_ln1_b  = (const float*)d_in[11];
  const float* c_ln2_s  = (const float*)d_in[12];
  const float* c_ln2_b  = (const float*)d_in[13];
  const float* c_q_w    = (const float*)d_in[14];
  const float* c_q_b    = (const float*)d_in[15];
  const float* c_kv_w   = (const float*)d_in[16];
  const float* c_kv_b   = (const float*)d_in[17];
  const float* c_proj_w = (const float*)d_in[18];
  const float* c_proj_b = (const float*)d_in[19];
  const float* c_ln3_s  = (const float*)d_in[20];
  const float* c_ln3_b  = (const float*)d_in[21];
  const float* c_mlp1_w = (const float*)d_in[22];
  const float* c_mlp1_b = (const float*)d_in[23];
  const float* c_mlp2_w = (const float*)d_in[24];
  const float* c_mlp2_b = (const float*)d_in[25];
  const float* s_ln1_s  = (const float*)d_in[26];
  const float* s_ln1_b  = (const float*)d_in[27];
  const float* s_qkv_w  = (const float*)d_in[28];
  const float* s_qkv_b  = (const float*)d_in[29];
  const float* s_proj_w = (const float*)d_in[30];
  const float* s_proj_b = (const float*)d_in[31];
  const float* s_ln2_s  = (const float*)d_in[32];
  const float* s_ln2_b  = (const float*)d_in[33];
  const float* s_mlp1_w = (const float*)d_in[34];
  const float* s_mlp1_b = (const float*)d_in[35];
  const float* s_mlp2_w = (const float*)d_in[36];
  const float* s_mlp2_b = (const float*)d_in[37];
  const float* lnpost_s = (const float*)d_in[38];
  const float* lnpost_b = (const float*)d_in[39];
  const float* out_w    = (const float*)d_in[40];
  const float* out_b    = (const float*)d_in[41];

  char* ws = (char*)d_ws;
  constexpr size_t MB = 1024 * 1024;
  unsigned short* embb = (unsigned short*)(ws);             // 16 MB bf16
  unsigned short* kbuf = (unsigned short*)(ws + 32 * MB);   // 16 MB bf16
  unsigned short* vbuf = (unsigned short*)(ws + 48 * MB);   // 16 MB bf16
  char*  b3   = ws + 64 * MB;
  float* dtok = (float*)(b3);
  float* hbuf = (float*)(b3 + 524288);
  unsigned short* qbuf = (unsigned short*)(b3 + 524288 + 1048576);
  unsigned short* mid = (unsigned short*)(b3 + 524288 + 3145728);
  unsigned short* qkv = (unsigned short*)(b3 + 524288 + 7340032);
  unsigned short* arena = (unsigned short*)(b3 + 524288 + 10485760);
  unsigned short* opart = (unsigned short*)(ws);
  float* lbuf  = (float*)(b3 + 16 * MB);

  const int IDK = 1 << 28;

  // 1) weight prep (all bf16) + dataset_emb (bf16)
  k_prep<<<(int)((AO_TOT + 255) / 256), 256, 0, stream>>>(
      c_q_w, c_kv_w, c_proj_w, c_mlp1_w, c_mlp2_w, s_qkv_w, s_proj_w,
      s_mlp1_w, s_mlp2_w, out_w, conv1_w, conv2_w, arena);
  k_posenc<<<2048, 256, 0, stream>>>(pts, pe_w, pe_b, embb);
  // 2+3) merged: gconv (256 blocks, 4pt) + single-pass KV LN-GEMM (2048)
  k_kvgc<<<2304, 256, 0, stream>>>(embb, arena + AO_WKV, c_kv_b, kbuf, vbuf,
                                   c_ln2_s, c_ln2_b, pts, arena + AO_W1B,
                                   conv1_b, arena + AO_W2B, conv2_b, dtok);
  // 4) concat + ln_pre -> h
  k_concat_ln<<<2048, 64, 0, stream>>>(dtok, otok, ln_pre_s, ln_pre_b, hbuf);
  // 5) cross attention block (S=32); Q pre-scaled bf16; comb fused into proj
  k_bgemm16<0, 1, 0><<<dim3(128, 2), 256, 0, stream>>>(
      hbuf, 128, arena + AO_WQ, c_q_b, nullptr, 0, qbuf, 128, 128, 0, c_ln1_s,
      c_ln1_b, IDK, 0, QSCALE, 128, nullptr, nullptr, 0);
  k_attn_mfma<<<1024, 256, 0, stream>>>(qbuf, 128, kbuf, 128, vbuf, 128,
                                        opart, lbuf, 8192, 32, 256);
  k_bgemm16<0, 0, 1><<<dim3(128, 2), 256, 0, stream>>>(
      nullptr, 128, arena + AO_WPROJC, c_proj_b, hbuf, 128, hbuf, 128, 128, 0,
      nullptr, nullptr, IDK, 0, 1.f, 0, opart, lbuf, 32);
  k_bgemm16<0, 1, 0><<<dim3(128, 8), 256, 0, stream>>>(
      hbuf, 128, arena + AO_WMLP1C, c_mlp1_b, nullptr, 0, mid, 512, 128, 1,
      c_ln3_s, c_ln3_b, IDK, 0, 1.f, 0, nullptr, nullptr, 0);
  k_bgemm16<1, 0, 0><<<dim3(128, 2), 256, 0, stream>>>(
      mid, 512, arena + AO_WMLP2C, c_mlp2_b, hbuf, 128, hbuf, 128, 512, 0,
      nullptr, nullptr, IDK, 0, 1.f, 0, nullptr, nullptr, 0);
  // 6) self-attention blocks (S=4), comb fused into proj
  for (int i = 0; i < 3; ++i) {
    k_bgemm16<0, 1, 0><<<dim3(128, 6), 256, 0, stream>>>(
        hbuf, 128, arena + AO_WQKVS + (size_t)i * 49152, s_qkv_b + i * 384,
        nullptr, 0, qkv, 384, 128, 0, s_ln1_s + i * 128, s_ln1_b + i * 128,
        IDK, 0, QSCALE, 128, nullptr, nullptr, 0);
    k_attn_mfma<<<128, 256, 0, stream>>>(qkv, 384, qkv + 128, 384, qkv + 256,
                                         384, opart, lbuf, 256, 4, 64);
    k_bgemm16<0, 0, 1><<<dim3(128, 2), 256, 0, stream>>>(
        nullptr, 128, arena + AO_WPROJS + (size_t)i * 16384,
        s_proj_b + i * 128, hbuf, 128, hbuf, 128, 128, 0, nullptr, nullptr,
        IDK, 0, 1.f, 0, opart, lbuf, 4);
    k_bgemm16<0, 1, 0><<<dim3(128, 8), 256, 0, stream>>>(
        hbuf, 128, arena + AO_WMLP1S + (size_t)i * 65536, s_mlp1_b + i * 512,
        nullptr, 0, mid, 512, 128, 1, s_ln2_s + i * 128, s_ln2_b + i * 128,
        IDK, 0, 1.f, 0, nullptr, nullptr, 0);
    k_bgemm16<1, 0, 0><<<dim3(128, 2), 256, 0, stream>>>(
        mid, 512, arena + AO_WMLP2S + (size_t)i * 65536, s_mlp2_b + i * 128,
        hbuf, 128, hbuf, 128, 512, 0, nullptr, nullptr, IDK, 0, 1.f, 0,
        nullptr, nullptr, 0);
  }
  // 7) final LN (last 128 tokens per batch) + output head with tanh
  k_bgemm16<0, 0, 0><<<dim3(64, 2), 256, 0, stream>>>(
      hbuf, 128, arena + AO_WOUT, out_b, nullptr, 0, (float*)d_out, 128, 128,
      2, lnpost_s, lnpost_b, 128, 128, 1.f, 0, nullptr, nullptr, 0);
}